// Round 1
// baseline (467.297 us; speedup 1.0000x reference)
//
#include <hip/hip_runtime.h>
#include <stdint.h>

#define NBOX 25200
#define NCH  16
#define TOPK 1024
#define NTH  1024
#define NPT  25          // ceil(25200/1024)
#define NBUCK 4096
#define CAP  2048        // candidate capacity (top-1024 + cutoff-bucket slack)

union Smem {
  struct { uint32_t hist[NBUCK]; uint32_t coarse[NTH]; } a;   // 20 KB
  struct { unsigned long long keys[CAP]; } b;                 // 16 KB
  struct { float bx1[TOPK], by1[TOPK], bx2[TOPK], by2[TOPK]; uint32_t keep[TOPK]; } c; // 20 KB
};

__device__ __forceinline__ uint32_t bucket_of(uint32_t bits) {
  // score in (0.25, 1): bits in [0x3E800001, 0x3F800000); monotonic in value
  uint32_t bk = (bits - 0x3E800001u) >> 12;
  return bk > (NBUCK - 1u) ? (NBUCK - 1u) : bk;
}

__global__ __launch_bounds__(NTH, 1) void nms_kernel(const float* __restrict__ x,
                                                     float* __restrict__ out) {
  __shared__ Smem sm;
  __shared__ int s_g, s_cut, s_cnt;
  __shared__ unsigned long long s_acc;

  const int t = threadIdx.x;
  const int b = blockIdx.x;
  const float* __restrict__ xb = x + (size_t)b * NBOX * NCH;

  // ---- Phase 0: scores into registers (one 64B line per row, ch4 & ch15 share it)
  float sc[NPT];
#pragma unroll
  for (int k = 0; k < NPT - 1; ++k) {
    const int i = t + k * NTH;
    const float p = xb[(size_t)i * NCH + 4] * xb[(size_t)i * NCH + 15];
    sc[k] = (p > 0.25f) ? p : -1.0f;
  }
  {
    const int i = t + (NPT - 1) * NTH;
    float s = -1.0f;
    if (i < NBOX) {
      const float p = xb[(size_t)i * NCH + 4] * xb[(size_t)i * NCH + 15];
      if (p > 0.25f) s = p;
    }
    sc[NPT - 1] = s;
  }

  // ---- Phase 1: histogram over score bits
  for (int j = t; j < NBUCK; j += NTH) sm.a.hist[j] = 0u;
  __syncthreads();
#pragma unroll
  for (int k = 0; k < NPT; ++k)
    if (sc[k] > 0.0f) atomicAdd(&sm.a.hist[bucket_of(__float_as_uint(sc[k]))], 1u);
  __syncthreads();

  // ---- Phase 2: cutoff = largest bucket c with suffix-count(c) >= TOPK
  {
    const uint32_t cs = sm.a.hist[4 * t] + sm.a.hist[4 * t + 1] +
                        sm.a.hist[4 * t + 2] + sm.a.hist[4 * t + 3];
    __syncthreads();
    sm.a.coarse[t] = cs;
  }
  __syncthreads();
  for (int off = 1; off < NTH; off <<= 1) {   // Hillis-Steele suffix scan
    uint32_t v = sm.a.coarse[t];
    if (t + off < NTH) v += sm.a.coarse[t + off];
    __syncthreads();
    sm.a.coarse[t] = v;
    __syncthreads();
  }
  if (t == 0) s_g = -1;
  __syncthreads();
  {
    const uint32_t suf = sm.a.coarse[t];
    const uint32_t sufn = (t + 1 < NTH) ? sm.a.coarse[t + 1] : 0u;
    if (suf >= TOPK && (t == NTH - 1 || sufn < TOPK)) s_g = t;
  }
  __syncthreads();
  if (t == 0) {
    int c = 0;
    const int g = s_g;
    if (g >= 0) {
      uint32_t S = sm.a.coarse[g];
      c = 4 * g;
      for (int j = 0; j < 3; ++j) {
        const uint32_t h = sm.a.hist[4 * g + j];
        if (S - h >= TOPK) { S -= h; ++c; } else break;
      }
    }
    s_cut = c;
    s_cnt = 0;
  }
  __syncthreads();
  const uint32_t cut = (uint32_t)s_cut;

  // ---- Phase 3: compact candidate keys (desc score, asc index tie-break)
#pragma unroll
  for (int k = 0; k < NPT; ++k) {
    if (sc[k] > 0.0f) {
      const uint32_t bits = __float_as_uint(sc[k]);
      if (bucket_of(bits) >= cut) {
        const int pos = atomicAdd(&s_cnt, 1);
        if (pos < CAP) {
          const uint32_t i = (uint32_t)(t + k * NTH);
          sm.b.keys[pos] = ((unsigned long long)bits << 32) |
                           (unsigned long long)(0xFFFFFFFFu - i);
        }
      }
    }
  }
  __syncthreads();
  {
    int M = s_cnt; if (M > CAP) M = CAP;
    for (int j = t; j < CAP; j += NTH) if (j >= M) sm.b.keys[j] = 0ull;
  }
  __syncthreads();

  // ---- Phase 4: bitonic sort 2048 keys, descending (disjoint pairs per step)
  for (int k2 = 2; k2 <= CAP; k2 <<= 1) {
    for (int j = k2 >> 1; j > 0; j >>= 1) {
      const int i = ((t & ~(j - 1)) << 1) | (t & (j - 1));
      const int l = i | j;
      const unsigned long long a = sm.b.keys[i];
      const unsigned long long bb = sm.b.keys[l];
      const bool dosw = ((i & k2) == 0) ? (a < bb) : (a > bb);
      if (dosw) { sm.b.keys[i] = bb; sm.b.keys[l] = a; }
      __syncthreads();
    }
  }

  // ---- Phase 5: take top-1024, gather rows, boxes to LDS
  const unsigned long long mykey = sm.b.keys[t];
  __syncthreads();   // before union reuse as .c

  const uint32_t sbits = (uint32_t)(mykey >> 32);
  const int src = (int)(0xFFFFFFFFu - (uint32_t)(mykey & 0xFFFFFFFFull));
  const bool valid = (sbits != 0u);
  const float conf = valid ? __uint_as_float(sbits) : 0.0f;

  float x1 = 0.f, y1 = 0.f, x2 = 0.f, y2 = 0.f;
  float lm0=0.f,lm1=0.f,lm2=0.f,lm3=0.f,lm4=0.f,lm5=0.f,lm6=0.f,lm7=0.f,lm8=0.f,lm9=0.f;
  if (valid) {
    const float4* rp = (const float4*)(xb + (size_t)src * NCH);
    const float4 q0 = rp[0], q1 = rp[1], q2 = rp[2], q3 = rp[3];
    x1 = q0.x - q0.z * 0.5f;
    y1 = q0.y - q0.w * 0.5f;
    x2 = q0.x + q0.z * 0.5f;
    y2 = q0.y + q0.w * 0.5f;
    lm0 = q1.y; lm1 = q1.z; lm2 = q1.w;
    lm3 = q2.x; lm4 = q2.y; lm5 = q2.z; lm6 = q2.w;
    lm7 = q3.x; lm8 = q3.y; lm9 = q3.z;
  }
  sm.c.bx1[t] = x1; sm.c.by1[t] = y1; sm.c.bx2[t] = x2; sm.c.by2[t] = y2;
  sm.c.keep[t] = valid ? 1u : 0u;
  __syncthreads();

  // ---- Phase 6: tiled greedy NMS (equivalent to sequential fori_loop)
  const float myarea = fmaxf(x2 - x1, 0.f) * fmaxf(y2 - y1, 0.f);
  uint32_t mykeep = valid ? 1u : 0u;

  for (int tile = 0; tile < TOPK / 64; ++tile) {
    // diagonal 64x64: wave 0, sequential greedy via ballot/shfl (no barriers)
    if (t < 64) {
      const int gi = tile * 64 + t;
      const float ax1 = sm.c.bx1[gi], ay1 = sm.c.by1[gi];
      const float ax2 = sm.c.bx2[gi], ay2 = sm.c.by2[gi];
      uint32_t kb = sm.c.keep[gi];
      const float aarea = fmaxf(ax2 - ax1, 0.f) * fmaxf(ay2 - ay1, 0.f);
      for (int i = 0; i < 63; ++i) {
        const unsigned long long bal = __ballot(kb != 0u);
        if ((bal >> i) & 1ull) {                      // wave-uniform
          const float ix1 = __shfl(ax1, i);
          const float iy1 = __shfl(ay1, i);
          const float ix2 = __shfl(ax2, i);
          const float iy2 = __shfl(ay2, i);
          const float ia  = __shfl(aarea, i);
          if (t > i && kb) {
            const float iw = fmaxf(fminf(ax2, ix2) - fmaxf(ax1, ix1), 0.f);
            const float ih = fmaxf(fminf(ay2, iy2) - fmaxf(ay1, iy1), 0.f);
            const float inter = iw * ih;
            const float uni = ia + aarea - inter;     // area_i + area_j, ref order
            if (inter / (uni + 1e-9f) > 0.45f) kb = 0u;
          }
        }
      }
      sm.c.keep[gi] = kb;
      const unsigned long long fin = __ballot(kb != 0u);
      if (t == 0) s_acc = fin;
    }
    __syncthreads();
    // apply this tile's survivors to all later boxes, in parallel
    const unsigned long long am = s_acc;
    if (t >= (tile + 1) * 64 && mykeep) {
      for (int i = 0; i < 64; ++i) {
        if ((am >> i) & 1ull) {
          const int gi = tile * 64 + i;
          const float ix1 = sm.c.bx1[gi], iy1 = sm.c.by1[gi];
          const float ix2 = sm.c.bx2[gi], iy2 = sm.c.by2[gi];
          const float ia = fmaxf(ix2 - ix1, 0.f) * fmaxf(iy2 - iy1, 0.f);
          const float iw = fmaxf(fminf(x2, ix2) - fmaxf(x1, ix1), 0.f);
          const float ih = fmaxf(fminf(y2, iy2) - fmaxf(y1, iy1), 0.f);
          const float inter = iw * ih;
          const float uni = ia + myarea - inter;
          if (inter / (uni + 1e-9f) > 0.45f) { mykeep = 0u; break; }
        }
      }
      if (!mykeep) sm.c.keep[t] = 0u;
    }
    __syncthreads();
  }

  // ---- Phase 7: write output row (16 floats), multiplied by keep
  const float m = sm.c.keep[t] ? 1.0f : 0.0f;
  float* __restrict__ ob = out + ((size_t)b * TOPK + (size_t)t) * NCH;
  float4* op = (float4*)ob;
  op[0] = make_float4(x1 * m, y1 * m, x2 * m, y2 * m);
  op[1] = make_float4(conf * m, lm0 * m, lm1 * m, lm2 * m);
  op[2] = make_float4(lm3 * m, lm4 * m, lm5 * m, lm6 * m);
  op[3] = make_float4(lm7 * m, lm8 * m, lm9 * m, 0.0f);
}

extern "C" void kernel_launch(void* const* d_in, const int* in_sizes, int n_in,
                              void* d_out, int out_size, void* d_ws, size_t ws_size,
                              hipStream_t stream) {
  const float* x = (const float*)d_in[0];
  float* out = (float*)d_out;
  nms_kernel<<<dim3(64), dim3(NTH), 0, stream>>>(x, out);
}